// Round 13
// baseline (328.693 us; speedup 1.0000x reference)
//
#include <hip/hip_runtime.h>
#include <math.h>

#define NN 100000
#define TWO_N 200000
#define NB 512          // buckets per graph
#define BSPAN 196       // node span per bucket (511*196 >= 100000)
#define B_TOT 1024      // buckets per plane
#define NBP2 2048       // 2 planes: [0,1024)=dst/CSR, [1024,2048)=src/degout
#define CHUNK 16384     // edges per multisplit block
#define NCP 256         // max chunks
#define LDSK 72         // padded k-stride (f16 elems) for h2 LDS bounce

struct __align__(4) h2_t { _Float16 x, y; };
struct __align__(8) h4_t { _Float16 v[4]; };
struct __align__(16) h8_t { _Float16 v[8]; };

typedef __attribute__((ext_vector_type(2))) _Float16 f16x2;
typedef __attribute__((ext_vector_type(8))) _Float16 f16x8;
typedef __attribute__((ext_vector_type(4))) _Float16 f16x4;
typedef __attribute__((ext_vector_type(4))) float    f32x4;

__device__ __forceinline__ float sigmoidf_(float x){ return 1.0f/(1.0f+__expf(-x)); }

// ---------------- multisplit CSR build (2 record planes, no global atomics) ----------------

__global__ __launch_bounds__(512) void k_hist(
    const int* __restrict__ s0, const int* __restrict__ d0,
    const int* __restrict__ s1, const int* __restrict__ d1, int E,
    int* __restrict__ histG){
  __shared__ int h[NBP2];
  int t = threadIdx.x;
  for(int i=t;i<NBP2;i+=512) h[i]=0;
  __syncthreads();
  int base = blockIdx.x*CHUNK, end = min(base+CHUNK, 2*E);
  for(int i=base+t; i<end; i+=512){
    int g = (i>=E); int le = g ? i-E : i;
    int dv = g ? d1[le] : d0[le];
    int sv = g ? s1[le] : s0[le];
    atomicAdd(&h[g*NB + dv/BSPAN], 1);
    atomicAdd(&h[B_TOT + g*NB + sv/BSPAN], 1);
  }
  __syncthreads();
  int* out = histG + blockIdx.x*NBP2;
  for(int b=t;b<NBP2;b+=512) out[b] = h[b];
}

__global__ __launch_bounds__(256) void k_cscan(
    const int* __restrict__ histG, int* __restrict__ offs,
    int* __restrict__ btot, int nchunk){
  __shared__ int s[256];
  int b = blockIdx.x, t = threadIdx.x;
  int v = (t < nchunk) ? histG[t*NBP2 + b] : 0;
  s[t] = v; __syncthreads();
  for(int off=1; off<256; off<<=1){
    int u = (t>=off) ? s[t-off] : 0;
    __syncthreads();
    s[t] += u;
    __syncthreads();
  }
  if(t < nchunk) offs[t*NBP2 + b] = s[t] - v;
  if(t == 255) btot[b] = s[255];
}

__global__ void k_bscan(const int* __restrict__ btot, int* __restrict__ bbase){
  __shared__ int s[B_TOT];
  int p = blockIdx.x, t = threadIdx.x;
  int v = btot[p*B_TOT + t]; s[t] = v; __syncthreads();
  for(int off=1; off<B_TOT; off<<=1){
    int u = (t>=off) ? s[t-off] : 0;
    __syncthreads();
    s[t] += u;
    __syncthreads();
  }
  bbase[p*B_TOT + t] = s[t] - v;
}

__global__ __launch_bounds__(512) void k_scatter2(
    const int* __restrict__ s0, const int* __restrict__ d0,
    const int* __restrict__ s1, const int* __restrict__ d1, int E,
    const int* __restrict__ bbase, const int* __restrict__ offs,
    unsigned* __restrict__ rbufA, unsigned char* __restrict__ rbufB){
  __shared__ int loff[NBP2];
  __shared__ int lcur[NBP2];
  int t = threadIdx.x;
  int chunk = blockIdx.x;
  const int* offc = offs + chunk*NBP2;
  for(int i=t;i<NBP2;i+=512){ loff[i] = bbase[i] + offc[i]; lcur[i] = 0; }
  __syncthreads();
  int base = chunk*CHUNK, end = min(base+CHUNK, 2*E);
  for(int i=base+t; i<end; i+=512){
    int g = (i>=E); int le = g ? i-E : i;
    int dv = g ? d1[le] : d0[le];
    int sv = g ? s1[le] : s0[le];
    int qb = dv / BSPAN;
    int qs = sv / BSPAN;
    int bA = g*NB + qb;
    int bB = B_TOT + g*NB + qs;
    int pA = atomicAdd(&lcur[bA], 1);
    rbufA[loff[bA] + pA] = ((unsigned)(g*NN + sv) << 8) | (unsigned)(dv - qb*BSPAN);
    int pB = atomicAdd(&lcur[bB], 1);
    rbufB[loff[bB] + pB] = (unsigned char)(sv - qs*BSPAN);
  }
}

__global__ __launch_bounds__(256) void k_build(
    const unsigned* __restrict__ rbufA, const unsigned char* __restrict__ rbufB,
    const int* __restrict__ btot, const int* __restrict__ bbase,
    int* __restrict__ deg_in, int* __restrict__ row_ptr, int* __restrict__ col,
    float* __restrict__ x0, float* __restrict__ rsout){
  __shared__ int hin[256];
  __shared__ int hout[256];
  __shared__ int offs[256];
  __shared__ int curs[256];
  int gb = blockIdx.x, t = threadIdx.x;
  int g = gb >> 9, b = gb & (NB-1);
  int node0 = b*BSPAN;
  int cntA = btot[gb],         baseA = bbase[gb];
  int cntB = btot[B_TOT + gb], baseB = bbase[B_TOT + gb];
  hin[t] = 0; hout[t] = 0;
  __syncthreads();
  for(int i=t; i<cntA; i+=256) atomicAdd(&hin[rbufA[baseA+i] & 255], 1);
  for(int i=t; i<cntB; i+=256) atomicAdd(&hout[(int)rbufB[baseB+i]], 1);
  __syncthreads();
  int v = hin[t]; offs[t] = v; __syncthreads();
  for(int off=1; off<256; off<<=1){
    int u = (t>=off) ? offs[t-off] : 0;
    __syncthreads();
    offs[t] += u;
    __syncthreads();
  }
  int excl = offs[t] - v;
  curs[t] = excl;
  int node = node0 + t;
  if(t < BSPAN && node < NN){
    int gnode = g*NN + node;
    int dou = hout[t];
    float ro = rsqrtf((float)(dou > 1 ? dou : 1));
    deg_in[gnode]  = v;
    row_ptr[gnode] = baseA + excl;
    rsout[gnode]   = ro;
    x0[gnode]      = (float)v * ro;
  }
  __syncthreads();
  for(int i=t; i<cntA; i+=256){
    unsigned r = rbufA[baseA+i];
    int slot = atomicAdd(&curs[r & 255], 1);
    col[baseA + slot] = (int)(r >> 8);
  }
}

// ---------------- layer-1 scalar gather (16 lanes per node) ----------------
__global__ void k_g1(const float* __restrict__ x0, const int* __restrict__ row_ptr,
                     const int* __restrict__ deg_in, const float* __restrict__ rsout,
                     const int* __restrict__ col, h2_t* __restrict__ av){
  int t = threadIdx.x;
  int wq = (blockIdx.x*blockDim.x + t) >> 4;   // node, 16 lanes each
  int sl = t & 15;
  if(wq >= TWO_N) return;
  int beg = row_ptr[wq], d = deg_in[wq];
  float r = 0.f;
  for(int e=sl; e<d; e+=16) r += x0[col[beg+e]];
  r += __shfl_xor(r,1); r += __shfl_xor(r,2); r += __shfl_xor(r,4); r += __shfl_xor(r,8);
  if(sl == 0){
    float a = r * rsqrtf((float)(d > 1 ? d : 1));
    h2_t o;
    o.x = (_Float16)a;
    o.y = (_Float16)rsout[wq];
    av[wq] = o;
  }
}

// ---------------- layer-2 hinge aggregation (wave per node, lane = j, LDS quad-broadcast) ----------------
__global__ __launch_bounds__(512) void k_g2a(
    const h2_t* __restrict__ av, const int* __restrict__ row_ptr,
    const int* __restrict__ deg_in, const int* __restrict__ col,
    const float* __restrict__ W1, const float* __restrict__ b1,
    _Float16* __restrict__ agg2){
  __shared__ float W1s[64], b1s[64];
  __shared__ unsigned stage[8][64];   // per-wave record staging (2 KB)
  int t = threadIdx.x;
  if(t < 64){ W1s[t] = W1[t]; b1s[t] = b1[t]; }
  __syncthreads();
  int w = t >> 6;
  int wid = (blockIdx.x*blockDim.x + t) >> 6;
  int lane = t & 63;
  if(wid >= TWO_N) return;
  int beg = row_ptr[wid], d = deg_in[wid];
  _Float16 w1h = (_Float16)W1s[lane], b1h = (_Float16)b1s[lane];
  f16x2 W1p = { w1h, w1h };
  f16x2 b1p = { b1h, b1h };
  const f16x2 zero2 = { (_Float16)0.f, (_Float16)0.f };
  unsigned* sp = &stage[w][0];
  float accx = 0.f;
  for(int base=0; base<d; base+=64){
    int cnt = min(64, d - base);
    unsigned pk = 0u;                 // zero-pad: a=0, rs=0 -> contribution 0
    int idx = base + lane;
    if(idx < d) pk = *(const unsigned*)&av[col[beg+idx]];
    sp[lane] = pk;
    asm volatile("s_waitcnt lgkmcnt(0)" ::: "memory");
    int quads = (cnt + 3) >> 2;
    int m = 0;
    while(m < quads){
      int stop = min(m + 8, quads);   // flush f16 accumulator every <=8 quads (16 addends)
      f16x2 accp = zero2;
      for(; m < stop; m++){
        uint4 uu = *(const uint4*)(sp + 4*m);   // ds_read_b128, wave-uniform addr (broadcast)
        unsigned ap0 = __builtin_amdgcn_perm(uu.y, uu.x, 0x05040100u);
        unsigned rp0 = __builtin_amdgcn_perm(uu.y, uu.x, 0x07060302u);
        unsigned ap1 = __builtin_amdgcn_perm(uu.w, uu.z, 0x05040100u);
        unsigned rp1 = __builtin_amdgcn_perm(uu.w, uu.z, 0x07060302u);
        f16x2 h0 = __builtin_bit_cast(f16x2, ap0)*W1p + b1p;
        h0 = __builtin_elementwise_max(h0, zero2);
        accp += h0*__builtin_bit_cast(f16x2, rp0);
        f16x2 h1 = __builtin_bit_cast(f16x2, ap1)*W1p + b1p;
        h1 = __builtin_elementwise_max(h1, zero2);
        accp += h1*__builtin_bit_cast(f16x2, rp1);
      }
      accx += (float)accp.x + (float)accp.y;
    }
    asm volatile("s_waitcnt lgkmcnt(0)" ::: "memory");  // reads done before next iter's writes
  }
  float agg = accx * rsqrtf((float)(d > 1 ? d : 1));
  float other = __shfl_xor(agg, 1);
  if(!(lane & 1)){
    h2_t o; o.x = (_Float16)agg; o.y = (_Float16)other;
    *(h2_t*)(agg2 + (size_t)wid*64 + lane) = o;
  }
}

// ---------------- MFMA fused GEMM: h2 = relu(agg2@W2+b2)*rs_out;  g3h8 = fp8(h2@W3) ----------------
__global__ __launch_bounds__(256) void k_mm(
    const _Float16* __restrict__ agg2, const h2_t* __restrict__ av,
    const float* __restrict__ W2, const float* __restrict__ b2,
    const float* __restrict__ W3, unsigned char* __restrict__ g3h8){
  __shared__ _Float16 h2s[4][16*LDSK];
  __shared__ unsigned char p8[4][16*32];
  int t = threadIdx.x;
  int w = t >> 6, lane = t & 63;
  int g = lane >> 4, c = lane & 15;
  int node0 = (blockIdx.x*4 + w)*16;

  f16x8 Bf2[2][4];
  #pragma unroll
  for(int kh=0; kh<2; kh++)
    #pragma unroll
    for(int nt=0; nt<4; nt++)
      #pragma unroll
      for(int e=0;e<8;e++)
        Bf2[kh][nt][e] = (_Float16)W2[(32*kh + 8*g + e)*64 + c + 16*nt];

  f16x8 Bf3[2][2];
  #pragma unroll
  for(int kh=0; kh<2; kh++)
    #pragma unroll
    for(int nt=0; nt<2; nt++)
      #pragma unroll
      for(int e=0;e<8;e++){
        int kp = 32*kh + 8*g + e;
        int j  = (kp>>2) + 16*(kp&3);
        Bf3[kh][nt][e] = (_Float16)W3[j*32 + c + 16*nt];
      }

  float b2r[4];
  #pragma unroll
  for(int nt=0;nt<4;nt++) b2r[nt] = b2[c + 16*nt];

  float rs[4];
  #pragma unroll
  for(int r=0;r<4;r++){
    union { unsigned u; h2_t h; } cv;
    cv.u = *(const unsigned*)&av[node0 + 4*g + r];
    rs[r] = (float)cv.h.y;
  }

  f16x8 A[2];
  #pragma unroll
  for(int kh=0;kh<2;kh++)
    A[kh] = *(const f16x8*)(agg2 + (size_t)(node0 + c)*64 + 32*kh + 8*g);

  f32x4 acc1[4];
  #pragma unroll
  for(int nt=0;nt<4;nt++){ acc1[nt][0]=0.f; acc1[nt][1]=0.f; acc1[nt][2]=0.f; acc1[nt][3]=0.f; }
  #pragma unroll
  for(int nt=0;nt<4;nt++){
    acc1[nt] = __builtin_amdgcn_mfma_f32_16x16x32_f16(A[0], Bf2[0][nt], acc1[nt], 0,0,0);
    acc1[nt] = __builtin_amdgcn_mfma_f32_16x16x32_f16(A[1], Bf2[1][nt], acc1[nt], 0,0,0);
  }

  _Float16* myh2 = h2s[w];
  #pragma unroll
  for(int r=0;r<4;r++){
    f16x4 pk4;
    #pragma unroll
    for(int nt=0;nt<4;nt++)
      pk4[nt] = (_Float16)(fmaxf(acc1[nt][r] + b2r[nt], 0.f) * rs[r]);
    *(f16x4*)(myh2 + (4*g + r)*LDSK + 4*c) = pk4;
  }
  asm volatile("s_waitcnt lgkmcnt(0)" ::: "memory");

  f16x8 A2[2];
  #pragma unroll
  for(int kh=0;kh<2;kh++)
    A2[kh] = *(const f16x8*)(myh2 + c*LDSK + 32*kh + 8*g);

  f32x4 acc2[2];
  #pragma unroll
  for(int nt=0;nt<2;nt++){ acc2[nt][0]=0.f; acc2[nt][1]=0.f; acc2[nt][2]=0.f; acc2[nt][3]=0.f; }
  #pragma unroll
  for(int nt=0;nt<2;nt++){
    acc2[nt] = __builtin_amdgcn_mfma_f32_16x16x32_f16(A2[0], Bf3[0][nt], acc2[nt], 0,0,0);
    acc2[nt] = __builtin_amdgcn_mfma_f32_16x16x32_f16(A2[1], Bf3[1][nt], acc2[nt], 0,0,0);
  }

  // fp8-encode into LDS byte tile, then coalesced 8B stores
  unsigned char* myp8 = p8[w];
  #pragma unroll
  for(int nt=0;nt<2;nt++)
    #pragma unroll
    for(int r=0;r<4;r++){
      float v = acc2[nt][r];
      int pk = __builtin_amdgcn_cvt_pk_fp8_f32(v, v, 0, false);
      myp8[(4*g + r)*32 + c + 16*nt] = (unsigned char)(pk & 0xff);
    }
  asm volatile("s_waitcnt lgkmcnt(0)" ::: "memory");
  unsigned char* dst = g3h8 + (size_t)node0*32;
  int row = lane >> 2, q8 = (lane & 3)*8;
  *(uint2*)(dst + row*32 + q8) = *(const uint2*)(myp8 + row*32 + q8);
}

// ---------------- layer3: 32-dim fp8 gather, 4 lanes/edge (8B), 16 edges in flight ----------------
__global__ void k_g3(const unsigned char* __restrict__ g3h8, const int* __restrict__ row_ptr,
                     const int* __restrict__ deg_in, const int* __restrict__ col,
                     const float* __restrict__ b3, _Float16* __restrict__ f){
  int t = threadIdx.x;
  int wid = (blockIdx.x*blockDim.x + t) >> 6;
  int lane = t & 63;
  if(wid >= TWO_N) return;
  int beg = row_ptr[wid], d = deg_in[wid];
  int q = lane >> 2, p = lane & 3;   // 16 edge slots x 4 lanes (8B each)
  float a[8] = {0.f,0.f,0.f,0.f,0.f,0.f,0.f,0.f};
  #pragma unroll 2
  for(int e=q; e<d; e+=16){
    int s = col[beg+e];
    uint2 u = *(const uint2*)(g3h8 + (size_t)s*32 + p*8);
    a[0] += __builtin_amdgcn_cvt_f32_fp8(u.x, 0);
    a[1] += __builtin_amdgcn_cvt_f32_fp8(u.x, 1);
    a[2] += __builtin_amdgcn_cvt_f32_fp8(u.x, 2);
    a[3] += __builtin_amdgcn_cvt_f32_fp8(u.x, 3);
    a[4] += __builtin_amdgcn_cvt_f32_fp8(u.y, 0);
    a[5] += __builtin_amdgcn_cvt_f32_fp8(u.y, 1);
    a[6] += __builtin_amdgcn_cvt_f32_fp8(u.y, 2);
    a[7] += __builtin_amdgcn_cvt_f32_fp8(u.y, 3);
  }
  #pragma unroll
  for(int m=4; m<64; m<<=1){
    #pragma unroll
    for(int k=0;k<8;k++) a[k] += __shfl_xor(a[k], m);
  }
  if(lane < 4){
    float rs = rsqrtf((float)(d > 1 ? d : 1));
    h8_t o;
    #pragma unroll
    for(int k=0;k<8;k++) o.v[k] = (_Float16)(a[k]*rs + b3[p*8+k]);
    *(h8_t*)(f + (size_t)wid*32 + p*8) = o;
  }
}

// ---------------- attention (batched) ----------------

__global__ void k_colmean(const _Float16* __restrict__ f, float* __restrict__ mean){
  int g = blockIdx.x >> 8;
  int t = threadIdx.x;
  int p = t & 15;
  int nodeLane = ((blockIdx.x & 255) << 4) | (t >> 4);
  float ax = 0.f, ay = 0.f;
  for(int n=nodeLane; n<NN; n+=4096){
    h2_t v = *(const h2_t*)(f + ((size_t)(g*NN + n))*32 + p*2);
    ax += (float)v.x; ay += (float)v.y;
  }
  __shared__ float sx[256], sy[256];
  sx[t] = ax; sy[t] = ay; __syncthreads();
  if(t < 16){
    float rx = 0.f, ry = 0.f;
    for(int k=0;k<16;k++){ rx += sx[k*16+t]; ry += sy[k*16+t]; }
    atomicAdd(&mean[g*32 + 2*t    ], rx);
    atomicAdd(&mean[g*32 + 2*t + 1], ry);
  }
}

__global__ void k_ctx(const float* __restrict__ mean, const float* __restrict__ W_att,
                      float* __restrict__ ctx){
  int t = threadIdx.x;   // 64 threads: 2 graphs x 32 dims
  int g = t >> 5, d = t & 31;
  float acc = 0.f;
  for(int i=0;i<32;i++) acc += (mean[g*32+i] * (1.0f/(float)NN)) * W_att[i*32 + d];
  ctx[t] = tanhf(acc);
}

__global__ void k_scores(const _Float16* __restrict__ f, const float* __restrict__ ctx,
                         float* __restrict__ evec){
  int g = blockIdx.x >> 8;
  int t = threadIdx.x;
  int p = t & 15;
  int nodeLane = ((blockIdx.x & 255) << 4) | (t >> 4);
  float cx = ctx[g*32 + 2*p], cy = ctx[g*32 + 2*p + 1];
  float ax = 0.f, ay = 0.f;
  for(int n=nodeLane; n<NN; n+=4096){
    h2_t v = *(const h2_t*)(f + ((size_t)(g*NN + n))*32 + p*2);
    float vx = (float)v.x, vy = (float)v.y;
    float dt = vx*cx + vy*cy;
    dt += __shfl_xor(dt,1); dt += __shfl_xor(dt,2);
    dt += __shfl_xor(dt,4); dt += __shfl_xor(dt,8);
    float sc = sigmoidf_(dt);
    ax += vx*sc; ay += vy*sc;
  }
  __shared__ float sx[256], sy[256];
  sx[t] = ax; sy[t] = ay; __syncthreads();
  if(t < 16){
    float rx = 0.f, ry = 0.f;
    for(int k=0;k<16;k++){ rx += sx[k*16+t]; ry += sy[k*16+t]; }
    atomicAdd(&evec[g*32 + 2*t    ], rx);
    atomicAdd(&evec[g*32 + 2*t + 1], ry);
  }
}

// ---------------- tiny head ----------------

__global__ void k_final(const float* __restrict__ evec,
                        const float* __restrict__ W_tn, const float* __restrict__ W_blk,
                        const float* __restrict__ b_tn, const float* __restrict__ W_fc,
                        const float* __restrict__ b_fc, const float* __restrict__ W_sc,
                        const float* __restrict__ b_sc, float* __restrict__ out){
  __shared__ float se0[32], se1[32], s_s[16], s2[16];
  int t = threadIdx.x;  // 64 threads
  if(t < 32){ se0[t] = evec[t]; se1[t] = evec[32 + t]; }
  __syncthreads();
  if(t < 16){
    float sc = 0.f;
    for(int i=0;i<32;i++){
      float a = se0[i];
      for(int j=0;j<32;j++) sc += a * W_tn[(i*32 + j)*16 + t] * se1[j];
    }
    float bl = 0.f;
    for(int k=0;k<32;k++) bl += W_blk[t*64 + k]      * se0[k];
    for(int k=0;k<32;k++) bl += W_blk[t*64 + 32 + k] * se1[k];
    s_s[t] = fmaxf(sc + bl + b_tn[t], 0.f);
  }
  __syncthreads();
  if(t < 16){
    float a = 0.f;
    for(int k=0;k<16;k++) a += s_s[k]*W_fc[k*16 + t];
    s2[t] = fmaxf(a + b_fc[t], 0.f);
  }
  __syncthreads();
  if(t == 0){
    float a = 0.f;
    for(int k=0;k<16;k++) a += s2[k]*W_sc[k];
    out[0] = sigmoidf_(a + b_sc[0]);
  }
}

// ---------------- launch ----------------

extern "C" void kernel_launch(void* const* d_in, const int* in_sizes, int n_in,
                              void* d_out, int out_size, void* d_ws, size_t ws_size,
                              hipStream_t stream){
  const int* s0 = (const int*)d_in[0];
  const int* dd0 = (const int*)d_in[1];
  const int* s1 = (const int*)d_in[2];
  const int* dd1 = (const int*)d_in[3];
  const float* W1  = (const float*)d_in[4];
  const float* b1  = (const float*)d_in[5];
  const float* W2  = (const float*)d_in[6];
  const float* b2  = (const float*)d_in[7];
  const float* W3  = (const float*)d_in[8];
  const float* b3  = (const float*)d_in[9];
  const float* W_att = (const float*)d_in[10];
  const float* W_tn  = (const float*)d_in[11];
  const float* W_blk = (const float*)d_in[12];
  const float* b_tn  = (const float*)d_in[13];
  const float* W_fc  = (const float*)d_in[14];
  const float* b_fc  = (const float*)d_in[15];
  const float* W_sc  = (const float*)d_in[16];
  const float* b_sc  = (const float*)d_in[17];
  const int E = in_sizes[0];
  const int nchunk = (2*E + CHUNK - 1)/CHUNK;   // 196 for E=1.6M

  char* w = (char*)d_ws;
  size_t off = 0;
  auto alloc = [&](size_t bytes)->void*{ void* p = w + off; off += (bytes + 255)/256*256; return p; };
  // zeroed region (one memset): mean, evec
  float* mean    = (float*)alloc(64*4);
  float* evec    = (float*)alloc(64*4);
  size_t zero_bytes = off;
  int*   histG   = (int*)alloc((size_t)NCP*NBP2*4);     // 2 MB
  int*   offsG   = (int*)alloc((size_t)NCP*NBP2*4);     // 2 MB
  int*   btot    = (int*)alloc(NBP2*4);
  int*   bbase   = (int*)alloc(NBP2*4);
  int*   deg_in  = (int*)alloc((size_t)TWO_N*4);
  int*   row_ptr = (int*)alloc((size_t)TWO_N*4);
  float* rsout   = (float*)alloc((size_t)TWO_N*4);
  int*   col     = (int*)alloc((size_t)2*E*4);
  float* x0      = (float*)alloc((size_t)TWO_N*4);
  h2_t*  av      = (h2_t*)alloc((size_t)TWO_N*4);
  _Float16* agg2 = (_Float16*)alloc((size_t)TWO_N*64*2);   // 25.6 MB
  unsigned char* g3h8 = (unsigned char*)alloc((size_t)TWO_N*32);  // 6.4 MB fp8
  float* ctx     = (float*)alloc(64*4);
  unsigned* rbufA      = (unsigned*)agg2;                        // 12.8 MB, dead before agg2
  unsigned char* rbufB = (unsigned char*)agg2 + (size_t)16*1024*1024;  // 3.2 MB, dead before agg2
  _Float16* f    = agg2;              // f aliases agg2 (agg2 dead after k_mm)

  hipMemsetAsync(d_ws, 0, zero_bytes, stream);

  k_hist    <<<nchunk,512,0,stream>>>(s0,dd0,s1,dd1,E,histG);
  k_cscan   <<<NBP2,256,0,stream>>>(histG,offsG,btot,nchunk);
  k_bscan   <<<2,B_TOT,0,stream>>>(btot,bbase);
  k_scatter2<<<nchunk,512,0,stream>>>(s0,dd0,s1,dd1,E,bbase,offsG,rbufA,rbufB);
  k_build   <<<B_TOT,256,0,stream>>>(rbufA,rbufB,btot,bbase,deg_in,row_ptr,col,x0,rsout);

  k_g1 <<<(TWO_N*16+511)/512,512,0,stream>>>(x0,row_ptr,deg_in,rsout,col,av);
  k_g2a<<<TWO_N/8,512,0,stream>>>(av,row_ptr,deg_in,col,W1,b1,agg2);
  k_mm <<<TWO_N/64,256,0,stream>>>(agg2,av,W2,b2,W3,g3h8);
  k_g3 <<<TWO_N/8,512,0,stream>>>(g3h8,row_ptr,deg_in,col,b3,f);

  k_colmean<<<512,256,0,stream>>>(f,mean);
  k_ctx<<<1,64,0,stream>>>(mean,W_att,ctx);
  k_scores<<<512,256,0,stream>>>(f,ctx,evec);

  k_final<<<1,64,0,stream>>>(evec,W_tn,W_blk,b_tn,W_fc,b_fc,W_sc,b_sc,(float*)d_out);
}

// Round 14
// 324.581 us; speedup vs baseline: 1.0127x; 1.0127x over previous
//
#include <hip/hip_runtime.h>
#include <math.h>

#define NN 100000
#define TWO_N 200000
#define NB 512          // buckets per graph
#define BSPAN 196       // node span per bucket (511*196 >= 100000)
#define B_TOT 1024      // buckets per plane
#define NBP2 2048       // 2 planes: [0,1024)=dst/CSR, [1024,2048)=src/degout
#define CHUNK 16384     // edges per multisplit block
#define NCP 256         // max chunks
#define LDSK 72         // padded k-stride (f16 elems) for h2 LDS bounce

struct __align__(4) h2_t { _Float16 x, y; };
struct __align__(8) h4_t { _Float16 v[4]; };

typedef __attribute__((ext_vector_type(2))) _Float16 f16x2;
typedef __attribute__((ext_vector_type(8))) _Float16 f16x8;
typedef __attribute__((ext_vector_type(4))) _Float16 f16x4;
typedef __attribute__((ext_vector_type(4))) float    f32x4;

__device__ __forceinline__ float sigmoidf_(float x){ return 1.0f/(1.0f+__expf(-x)); }

// ---------------- multisplit CSR build (2 record planes, no global atomics) ----------------

__global__ __launch_bounds__(512) void k_hist(
    const int* __restrict__ s0, const int* __restrict__ d0,
    const int* __restrict__ s1, const int* __restrict__ d1, int E,
    int* __restrict__ histG){
  __shared__ int h[NBP2];
  int t = threadIdx.x;
  for(int i=t;i<NBP2;i+=512) h[i]=0;
  __syncthreads();
  int base = blockIdx.x*CHUNK, end = min(base+CHUNK, 2*E);
  for(int i=base+t; i<end; i+=512){
    int g = (i>=E); int le = g ? i-E : i;
    int dv = g ? d1[le] : d0[le];
    int sv = g ? s1[le] : s0[le];
    atomicAdd(&h[g*NB + dv/BSPAN], 1);
    atomicAdd(&h[B_TOT + g*NB + sv/BSPAN], 1);
  }
  __syncthreads();
  int* out = histG + blockIdx.x*NBP2;
  for(int b=t;b<NBP2;b+=512) out[b] = h[b];
}

__global__ __launch_bounds__(256) void k_cscan(
    const int* __restrict__ histG, int* __restrict__ offs,
    int* __restrict__ btot, int nchunk){
  __shared__ int s[256];
  int b = blockIdx.x, t = threadIdx.x;
  int v = (t < nchunk) ? histG[t*NBP2 + b] : 0;
  s[t] = v; __syncthreads();
  for(int off=1; off<256; off<<=1){
    int u = (t>=off) ? s[t-off] : 0;
    __syncthreads();
    s[t] += u;
    __syncthreads();
  }
  if(t < nchunk) offs[t*NBP2 + b] = s[t] - v;
  if(t == 255) btot[b] = s[255];
}

__global__ void k_bscan(const int* __restrict__ btot, int* __restrict__ bbase){
  __shared__ int s[B_TOT];
  int p = blockIdx.x, t = threadIdx.x;
  int v = btot[p*B_TOT + t]; s[t] = v; __syncthreads();
  for(int off=1; off<B_TOT; off<<=1){
    int u = (t>=off) ? s[t-off] : 0;
    __syncthreads();
    s[t] += u;
    __syncthreads();
  }
  bbase[p*B_TOT + t] = s[t] - v;
}

__global__ __launch_bounds__(512) void k_scatter2(
    const int* __restrict__ s0, const int* __restrict__ d0,
    const int* __restrict__ s1, const int* __restrict__ d1, int E,
    const int* __restrict__ bbase, const int* __restrict__ offs,
    unsigned* __restrict__ rbufA, unsigned char* __restrict__ rbufB){
  __shared__ int loff[NBP2];
  __shared__ int lcur[NBP2];
  int t = threadIdx.x;
  int chunk = blockIdx.x;
  const int* offc = offs + chunk*NBP2;
  for(int i=t;i<NBP2;i+=512){ loff[i] = bbase[i] + offc[i]; lcur[i] = 0; }
  __syncthreads();
  int base = chunk*CHUNK, end = min(base+CHUNK, 2*E);
  for(int i=base+t; i<end; i+=512){
    int g = (i>=E); int le = g ? i-E : i;
    int dv = g ? d1[le] : d0[le];
    int sv = g ? s1[le] : s0[le];
    int qb = dv / BSPAN;
    int qs = sv / BSPAN;
    int bA = g*NB + qb;
    int bB = B_TOT + g*NB + qs;
    int pA = atomicAdd(&lcur[bA], 1);
    rbufA[loff[bA] + pA] = ((unsigned)(g*NN + sv) << 8) | (unsigned)(dv - qb*BSPAN);
    int pB = atomicAdd(&lcur[bB], 1);
    rbufB[loff[bB] + pB] = (unsigned char)(sv - qs*BSPAN);
  }
}

__global__ __launch_bounds__(256) void k_build(
    const unsigned* __restrict__ rbufA, const unsigned char* __restrict__ rbufB,
    const int* __restrict__ btot, const int* __restrict__ bbase,
    int* __restrict__ deg_in, int* __restrict__ row_ptr, int* __restrict__ col,
    float* __restrict__ x0, float* __restrict__ rsout){
  __shared__ int hin[256];
  __shared__ int hout[256];
  __shared__ int offs[256];
  __shared__ int curs[256];
  int gb = blockIdx.x, t = threadIdx.x;
  int g = gb >> 9, b = gb & (NB-1);
  int node0 = b*BSPAN;
  int cntA = btot[gb],         baseA = bbase[gb];
  int cntB = btot[B_TOT + gb], baseB = bbase[B_TOT + gb];
  hin[t] = 0; hout[t] = 0;
  __syncthreads();
  for(int i=t; i<cntA; i+=256) atomicAdd(&hin[rbufA[baseA+i] & 255], 1);
  for(int i=t; i<cntB; i+=256) atomicAdd(&hout[(int)rbufB[baseB+i]], 1);
  __syncthreads();
  int v = hin[t]; offs[t] = v; __syncthreads();
  for(int off=1; off<256; off<<=1){
    int u = (t>=off) ? offs[t-off] : 0;
    __syncthreads();
    offs[t] += u;
    __syncthreads();
  }
  int excl = offs[t] - v;
  curs[t] = excl;
  int node = node0 + t;
  if(t < BSPAN && node < NN){
    int gnode = g*NN + node;
    int dou = hout[t];
    float ro = rsqrtf((float)(dou > 1 ? dou : 1));
    deg_in[gnode]  = v;
    row_ptr[gnode] = baseA + excl;
    rsout[gnode]   = ro;
    x0[gnode]      = (float)v * ro;
  }
  __syncthreads();
  for(int i=t; i<cntA; i+=256){
    unsigned r = rbufA[baseA+i];
    int slot = atomicAdd(&curs[r & 255], 1);
    col[baseA + slot] = (int)(r >> 8);
  }
}

// ---------------- layer-1 scalar gather (16 lanes per node) ----------------
__global__ void k_g1(const float* __restrict__ x0, const int* __restrict__ row_ptr,
                     const int* __restrict__ deg_in, const float* __restrict__ rsout,
                     const int* __restrict__ col, h2_t* __restrict__ av){
  int t = threadIdx.x;
  int wq = (blockIdx.x*blockDim.x + t) >> 4;   // node, 16 lanes each
  int sl = t & 15;
  if(wq >= TWO_N) return;
  int beg = row_ptr[wq], d = deg_in[wq];
  float r = 0.f;
  for(int e=sl; e<d; e+=16) r += x0[col[beg+e]];
  r += __shfl_xor(r,1); r += __shfl_xor(r,2); r += __shfl_xor(r,4); r += __shfl_xor(r,8);
  if(sl == 0){
    float a = r * rsqrtf((float)(d > 1 ? d : 1));
    h2_t o;
    o.x = (_Float16)a;
    o.y = (_Float16)rsout[wq];
    av[wq] = o;
  }
}

// ---------------- layer-2 hinge aggregation (wave per node, lane = j, LDS quad-broadcast) ----------------
__global__ __launch_bounds__(512) void k_g2a(
    const h2_t* __restrict__ av, const int* __restrict__ row_ptr,
    const int* __restrict__ deg_in, const int* __restrict__ col,
    const float* __restrict__ W1, const float* __restrict__ b1,
    _Float16* __restrict__ agg2){
  __shared__ float W1s[64], b1s[64];
  __shared__ unsigned stage[8][64];   // per-wave record staging (2 KB)
  int t = threadIdx.x;
  if(t < 64){ W1s[t] = W1[t]; b1s[t] = b1[t]; }
  __syncthreads();
  int w = t >> 6;
  int wid = (blockIdx.x*blockDim.x + t) >> 6;
  int lane = t & 63;
  if(wid >= TWO_N) return;
  int beg = row_ptr[wid], d = deg_in[wid];
  _Float16 w1h = (_Float16)W1s[lane], b1h = (_Float16)b1s[lane];
  f16x2 W1p = { w1h, w1h };
  f16x2 b1p = { b1h, b1h };
  const f16x2 zero2 = { (_Float16)0.f, (_Float16)0.f };
  unsigned* sp = &stage[w][0];
  float accx = 0.f;
  for(int base=0; base<d; base+=64){
    int cnt = min(64, d - base);
    unsigned pk = 0u;                 // zero-pad: a=0, rs=0 -> contribution 0
    int idx = base + lane;
    if(idx < d) pk = *(const unsigned*)&av[col[beg+idx]];
    sp[lane] = pk;
    asm volatile("s_waitcnt lgkmcnt(0)" ::: "memory");
    int quads = (cnt + 3) >> 2;
    int m = 0;
    while(m < quads){
      int stop = min(m + 8, quads);   // flush f16 accumulator every <=8 quads (16 addends)
      f16x2 accp = zero2;
      for(; m < stop; m++){
        uint4 uu = *(const uint4*)(sp + 4*m);   // ds_read_b128, wave-uniform addr (broadcast)
        unsigned ap0 = __builtin_amdgcn_perm(uu.y, uu.x, 0x05040100u);
        unsigned rp0 = __builtin_amdgcn_perm(uu.y, uu.x, 0x07060302u);
        unsigned ap1 = __builtin_amdgcn_perm(uu.w, uu.z, 0x05040100u);
        unsigned rp1 = __builtin_amdgcn_perm(uu.w, uu.z, 0x07060302u);
        f16x2 h0 = __builtin_bit_cast(f16x2, ap0)*W1p + b1p;
        h0 = __builtin_elementwise_max(h0, zero2);
        accp += h0*__builtin_bit_cast(f16x2, rp0);
        f16x2 h1 = __builtin_bit_cast(f16x2, ap1)*W1p + b1p;
        h1 = __builtin_elementwise_max(h1, zero2);
        accp += h1*__builtin_bit_cast(f16x2, rp1);
      }
      accx += (float)accp.x + (float)accp.y;
    }
    asm volatile("s_waitcnt lgkmcnt(0)" ::: "memory");  // reads done before next iter's writes
  }
  float agg = accx * rsqrtf((float)(d > 1 ? d : 1));
  float other = __shfl_xor(agg, 1);
  if(!(lane & 1)){
    h2_t o; o.x = (_Float16)agg; o.y = (_Float16)other;
    *(h2_t*)(agg2 + (size_t)wid*64 + lane) = o;
  }
}

// ---------------- MFMA fused GEMM: h2 = relu(agg2@W2+b2)*rs_out;  g3h8 = fp8(h2@W3) ----------------
__global__ __launch_bounds__(256) void k_mm(
    const _Float16* __restrict__ agg2, const h2_t* __restrict__ av,
    const float* __restrict__ W2, const float* __restrict__ b2,
    const float* __restrict__ W3, unsigned char* __restrict__ g3h8){
  __shared__ _Float16 h2s[4][16*LDSK];
  __shared__ unsigned char p8[4][16*32];
  int t = threadIdx.x;
  int w = t >> 6, lane = t & 63;
  int g = lane >> 4, c = lane & 15;
  int node0 = (blockIdx.x*4 + w)*16;

  f16x8 Bf2[2][4];
  #pragma unroll
  for(int kh=0; kh<2; kh++)
    #pragma unroll
    for(int nt=0; nt<4; nt++)
      #pragma unroll
      for(int e=0;e<8;e++)
        Bf2[kh][nt][e] = (_Float16)W2[(32*kh + 8*g + e)*64 + c + 16*nt];

  f16x8 Bf3[2][2];
  #pragma unroll
  for(int kh=0; kh<2; kh++)
    #pragma unroll
    for(int nt=0; nt<2; nt++)
      #pragma unroll
      for(int e=0;e<8;e++){
        int kp = 32*kh + 8*g + e;
        int j  = (kp>>2) + 16*(kp&3);
        Bf3[kh][nt][e] = (_Float16)W3[j*32 + c + 16*nt];
      }

  float b2r[4];
  #pragma unroll
  for(int nt=0;nt<4;nt++) b2r[nt] = b2[c + 16*nt];

  float rs[4];
  #pragma unroll
  for(int r=0;r<4;r++){
    union { unsigned u; h2_t h; } cv;
    cv.u = *(const unsigned*)&av[node0 + 4*g + r];
    rs[r] = (float)cv.h.y;
  }

  f16x8 A[2];
  #pragma unroll
  for(int kh=0;kh<2;kh++)
    A[kh] = *(const f16x8*)(agg2 + (size_t)(node0 + c)*64 + 32*kh + 8*g);

  f32x4 acc1[4];
  #pragma unroll
  for(int nt=0;nt<4;nt++){ acc1[nt][0]=0.f; acc1[nt][1]=0.f; acc1[nt][2]=0.f; acc1[nt][3]=0.f; }
  #pragma unroll
  for(int nt=0;nt<4;nt++){
    acc1[nt] = __builtin_amdgcn_mfma_f32_16x16x32_f16(A[0], Bf2[0][nt], acc1[nt], 0,0,0);
    acc1[nt] = __builtin_amdgcn_mfma_f32_16x16x32_f16(A[1], Bf2[1][nt], acc1[nt], 0,0,0);
  }

  _Float16* myh2 = h2s[w];
  #pragma unroll
  for(int r=0;r<4;r++){
    f16x4 pk4;
    #pragma unroll
    for(int nt=0;nt<4;nt++)
      pk4[nt] = (_Float16)(fmaxf(acc1[nt][r] + b2r[nt], 0.f) * rs[r]);
    *(f16x4*)(myh2 + (4*g + r)*LDSK + 4*c) = pk4;
  }
  asm volatile("s_waitcnt lgkmcnt(0)" ::: "memory");

  f16x8 A2[2];
  #pragma unroll
  for(int kh=0;kh<2;kh++)
    A2[kh] = *(const f16x8*)(myh2 + c*LDSK + 32*kh + 8*g);

  f32x4 acc2[2];
  #pragma unroll
  for(int nt=0;nt<2;nt++){ acc2[nt][0]=0.f; acc2[nt][1]=0.f; acc2[nt][2]=0.f; acc2[nt][3]=0.f; }
  #pragma unroll
  for(int nt=0;nt<2;nt++){
    acc2[nt] = __builtin_amdgcn_mfma_f32_16x16x32_f16(A2[0], Bf3[0][nt], acc2[nt], 0,0,0);
    acc2[nt] = __builtin_amdgcn_mfma_f32_16x16x32_f16(A2[1], Bf3[1][nt], acc2[nt], 0,0,0);
  }

  // fp8-encode into LDS byte tile, then coalesced 8B stores
  unsigned char* myp8 = p8[w];
  #pragma unroll
  for(int nt=0;nt<2;nt++)
    #pragma unroll
    for(int r=0;r<4;r++){
      float v = acc2[nt][r];
      int pk = __builtin_amdgcn_cvt_pk_fp8_f32(v, v, 0, false);
      myp8[(4*g + r)*32 + c + 16*nt] = (unsigned char)(pk & 0xff);
    }
  asm volatile("s_waitcnt lgkmcnt(0)" ::: "memory");
  unsigned char* dst = g3h8 + (size_t)node0*32;
  int row = lane >> 2, q8 = (lane & 3)*8;
  *(uint2*)(dst + row*32 + q8) = *(const uint2*)(myp8 + row*32 + q8);
}

// ---------------- layer3: 32-dim fp8 gather (32B/edge, 8 lanes/edge) ----------------
__global__ void k_g3(const unsigned char* __restrict__ g3h8, const int* __restrict__ row_ptr,
                     const int* __restrict__ deg_in, const int* __restrict__ col,
                     const float* __restrict__ b3, _Float16* __restrict__ f){
  int t = threadIdx.x;
  int wid = (blockIdx.x*blockDim.x + t) >> 6;
  int lane = t & 63;
  if(wid >= TWO_N) return;
  int beg = row_ptr[wid], d = deg_in[wid];
  int q = lane >> 3, p = lane & 7;
  float a0=0.f, a1=0.f, a2=0.f, a3=0.f;
  #pragma unroll 2
  for(int e=q; e<d; e+=8){
    int s = col[beg+e];
    int u = *(const int*)(g3h8 + (size_t)s*32 + p*4);
    a0 += __builtin_amdgcn_cvt_f32_fp8(u, 0);
    a1 += __builtin_amdgcn_cvt_f32_fp8(u, 1);
    a2 += __builtin_amdgcn_cvt_f32_fp8(u, 2);
    a3 += __builtin_amdgcn_cvt_f32_fp8(u, 3);
  }
  #pragma unroll
  for(int m=8; m<64; m<<=1){
    a0 += __shfl_xor(a0,m); a1 += __shfl_xor(a1,m);
    a2 += __shfl_xor(a2,m); a3 += __shfl_xor(a3,m);
  }
  if(lane < 8){
    float rs = rsqrtf((float)(d > 1 ? d : 1));
    h4_t o;
    o.v[0] = (_Float16)(a0*rs + b3[p*4+0]);
    o.v[1] = (_Float16)(a1*rs + b3[p*4+1]);
    o.v[2] = (_Float16)(a2*rs + b3[p*4+2]);
    o.v[3] = (_Float16)(a3*rs + b3[p*4+3]);
    *(h4_t*)(f + (size_t)wid*32 + p*4) = o;
  }
}

// ---------------- attention (batched) ----------------

__global__ void k_colmean(const _Float16* __restrict__ f, float* __restrict__ mean){
  int g = blockIdx.x >> 8;
  int t = threadIdx.x;
  int p = t & 15;
  int nodeLane = ((blockIdx.x & 255) << 4) | (t >> 4);
  float ax = 0.f, ay = 0.f;
  for(int n=nodeLane; n<NN; n+=4096){
    h2_t v = *(const h2_t*)(f + ((size_t)(g*NN + n))*32 + p*2);
    ax += (float)v.x; ay += (float)v.y;
  }
  __shared__ float sx[256], sy[256];
  sx[t] = ax; sy[t] = ay; __syncthreads();
  if(t < 16){
    float rx = 0.f, ry = 0.f;
    for(int k=0;k<16;k++){ rx += sx[k*16+t]; ry += sy[k*16+t]; }
    atomicAdd(&mean[g*32 + 2*t    ], rx);
    atomicAdd(&mean[g*32 + 2*t + 1], ry);
  }
}

__global__ void k_ctx(const float* __restrict__ mean, const float* __restrict__ W_att,
                      float* __restrict__ ctx){
  int t = threadIdx.x;   // 64 threads: 2 graphs x 32 dims
  int g = t >> 5, d = t & 31;
  float acc = 0.f;
  for(int i=0;i<32;i++) acc += (mean[g*32+i] * (1.0f/(float)NN)) * W_att[i*32 + d];
  ctx[t] = tanhf(acc);
}

__global__ void k_scores(const _Float16* __restrict__ f, const float* __restrict__ ctx,
                         float* __restrict__ evec){
  int g = blockIdx.x >> 8;
  int t = threadIdx.x;
  int p = t & 15;
  int nodeLane = ((blockIdx.x & 255) << 4) | (t >> 4);
  float cx = ctx[g*32 + 2*p], cy = ctx[g*32 + 2*p + 1];
  float ax = 0.f, ay = 0.f;
  for(int n=nodeLane; n<NN; n+=4096){
    h2_t v = *(const h2_t*)(f + ((size_t)(g*NN + n))*32 + p*2);
    float vx = (float)v.x, vy = (float)v.y;
    float dt = vx*cx + vy*cy;
    dt += __shfl_xor(dt,1); dt += __shfl_xor(dt,2);
    dt += __shfl_xor(dt,4); dt += __shfl_xor(dt,8);
    float sc = sigmoidf_(dt);
    ax += vx*sc; ay += vy*sc;
  }
  __shared__ float sx[256], sy[256];
  sx[t] = ax; sy[t] = ay; __syncthreads();
  if(t < 16){
    float rx = 0.f, ry = 0.f;
    for(int k=0;k<16;k++){ rx += sx[k*16+t]; ry += sy[k*16+t]; }
    atomicAdd(&evec[g*32 + 2*t    ], rx);
    atomicAdd(&evec[g*32 + 2*t + 1], ry);
  }
}

// ---------------- tiny head ----------------

__global__ void k_final(const float* __restrict__ evec,
                        const float* __restrict__ W_tn, const float* __restrict__ W_blk,
                        const float* __restrict__ b_tn, const float* __restrict__ W_fc,
                        const float* __restrict__ b_fc, const float* __restrict__ W_sc,
                        const float* __restrict__ b_sc, float* __restrict__ out){
  __shared__ float se0[32], se1[32], s_s[16], s2[16];
  int t = threadIdx.x;  // 64 threads
  if(t < 32){ se0[t] = evec[t]; se1[t] = evec[32 + t]; }
  __syncthreads();
  if(t < 16){
    float sc = 0.f;
    for(int i=0;i<32;i++){
      float a = se0[i];
      for(int j=0;j<32;j++) sc += a * W_tn[(i*32 + j)*16 + t] * se1[j];
    }
    float bl = 0.f;
    for(int k=0;k<32;k++) bl += W_blk[t*64 + k]      * se0[k];
    for(int k=0;k<32;k++) bl += W_blk[t*64 + 32 + k] * se1[k];
    s_s[t] = fmaxf(sc + bl + b_tn[t], 0.f);
  }
  __syncthreads();
  if(t < 16){
    float a = 0.f;
    for(int k=0;k<16;k++) a += s_s[k]*W_fc[k*16 + t];
    s2[t] = fmaxf(a + b_fc[t], 0.f);
  }
  __syncthreads();
  if(t == 0){
    float a = 0.f;
    for(int k=0;k<16;k++) a += s2[k]*W_sc[k];
    out[0] = sigmoidf_(a + b_sc[0]);
  }
}

// ---------------- launch ----------------

extern "C" void kernel_launch(void* const* d_in, const int* in_sizes, int n_in,
                              void* d_out, int out_size, void* d_ws, size_t ws_size,
                              hipStream_t stream){
  const int* s0 = (const int*)d_in[0];
  const int* dd0 = (const int*)d_in[1];
  const int* s1 = (const int*)d_in[2];
  const int* dd1 = (const int*)d_in[3];
  const float* W1  = (const float*)d_in[4];
  const float* b1  = (const float*)d_in[5];
  const float* W2  = (const float*)d_in[6];
  const float* b2  = (const float*)d_in[7];
  const float* W3  = (const float*)d_in[8];
  const float* b3  = (const float*)d_in[9];
  const float* W_att = (const float*)d_in[10];
  const float* W_tn  = (const float*)d_in[11];
  const float* W_blk = (const float*)d_in[12];
  const float* b_tn  = (const float*)d_in[13];
  const float* W_fc  = (const float*)d_in[14];
  const float* b_fc  = (const float*)d_in[15];
  const float* W_sc  = (const float*)d_in[16];
  const float* b_sc  = (const float*)d_in[17];
  const int E = in_sizes[0];
  const int nchunk = (2*E + CHUNK - 1)/CHUNK;   // 196 for E=1.6M

  char* w = (char*)d_ws;
  size_t off = 0;
  auto alloc = [&](size_t bytes)->void*{ void* p = w + off; off += (bytes + 255)/256*256; return p; };
  // zeroed region (one memset): mean, evec
  float* mean    = (float*)alloc(64*4);
  float* evec    = (float*)alloc(64*4);
  size_t zero_bytes = off;
  int*   histG   = (int*)alloc((size_t)NCP*NBP2*4);     // 2 MB
  int*   offsG   = (int*)alloc((size_t)NCP*NBP2*4);     // 2 MB
  int*   btot    = (int*)alloc(NBP2*4);
  int*   bbase   = (int*)alloc(NBP2*4);
  int*   deg_in  = (int*)alloc((size_t)TWO_N*4);
  int*   row_ptr = (int*)alloc((size_t)TWO_N*4);
  float* rsout   = (float*)alloc((size_t)TWO_N*4);
  int*   col     = (int*)alloc((size_t)2*E*4);
  float* x0      = (float*)alloc((size_t)TWO_N*4);
  h2_t*  av      = (h2_t*)alloc((size_t)TWO_N*4);
  _Float16* agg2 = (_Float16*)alloc((size_t)TWO_N*64*2);   // 25.6 MB
  unsigned char* g3h8 = (unsigned char*)alloc((size_t)TWO_N*32);  // 6.4 MB fp8
  float* ctx     = (float*)alloc(64*4);
  unsigned* rbufA      = (unsigned*)agg2;                        // 12.8 MB, dead before agg2
  unsigned char* rbufB = (unsigned char*)agg2 + (size_t)16*1024*1024;  // 3.2 MB, dead before agg2
  _Float16* f    = agg2;              // f aliases agg2 (agg2 dead after k_mm)

  hipMemsetAsync(d_ws, 0, zero_bytes, stream);

  k_hist    <<<nchunk,512,0,stream>>>(s0,dd0,s1,dd1,E,histG);
  k_cscan   <<<NBP2,256,0,stream>>>(histG,offsG,btot,nchunk);
  k_bscan   <<<2,B_TOT,0,stream>>>(btot,bbase);
  k_scatter2<<<nchunk,512,0,stream>>>(s0,dd0,s1,dd1,E,bbase,offsG,rbufA,rbufB);
  k_build   <<<B_TOT,256,0,stream>>>(rbufA,rbufB,btot,bbase,deg_in,row_ptr,col,x0,rsout);

  k_g1 <<<(TWO_N*16+511)/512,512,0,stream>>>(x0,row_ptr,deg_in,rsout,col,av);
  k_g2a<<<TWO_N/8,512,0,stream>>>(av,row_ptr,deg_in,col,W1,b1,agg2);
  k_mm <<<TWO_N/64,256,0,stream>>>(agg2,av,W2,b2,W3,g3h8);
  k_g3 <<<TWO_N/8,512,0,stream>>>(g3h8,row_ptr,deg_in,col,b3,f);

  k_colmean<<<512,256,0,stream>>>(f,mean);
  k_ctx<<<1,64,0,stream>>>(mean,W_att,ctx);
  k_scores<<<512,256,0,stream>>>(f,ctx,evec);

  k_final<<<1,64,0,stream>>>(evec,W_tn,W_blk,b_tn,W_fc,b_fc,W_sc,b_sc,(float*)d_out);
}